// Round 11
// baseline (214.178 us; speedup 1.0000x reference)
//
#include <hip/hip_runtime.h>
#include <hip/hip_bf16.h>
#include <cstdint>

// SelfAttention fused pipeline, MI355X gfx950. Round 11:
//  R8 base (best: 194.7us) + cvt3 ELIMINATED by fusing fp32->f16 into proj's
//  A-staging (reg-staged, T14 async-split: loads@p0/p4, cvt+ds_write@p2/p6,
//  B via gld_lds@p2; ONE barrier per K-tile: vmcnt(4)+lgkmcnt(0)@p0).
//  qk/pv/softmax/LN: exact R8.
// B=4, S=2048, D=1024. fp32 in/out; fp16 MFMA internally.
//
// ws layout (MB offsets): 0 qf16(16) | 16 kf16(16) | 32 vT(16) | 48/50/52 wt
// | 54 O0 f16(16) | 70 O1 f16(16) | 118 Sbuf fp32(64) | 182 Pbuf f16(32).

typedef unsigned short u16;
typedef unsigned int   u32;
typedef _Float16 f16;
typedef f16   f16x8  __attribute__((ext_vector_type(8)));
typedef f16   f16x4  __attribute__((ext_vector_type(4)));
typedef float f32x4  __attribute__((ext_vector_type(4)));

#define DEV __device__ __forceinline__

// async global->LDS, 16B per lane. LDS dest linear (uniform base + lane*16).
DEV void gld_lds16(const f16* g, char* l){
  __builtin_amdgcn_global_load_lds(
      (const __attribute__((address_space(1))) u32*)(uintptr_t)g,
      (__attribute__((address_space(3))) u32*)(u32)(uintptr_t)l, 16, 0, 0);
}

// T1: bijective XCD-contiguous remap of the linearized block id.
DEV int swz_lid(){
  int lid = (blockIdx.z * gridDim.y + blockIdx.y) * gridDim.x + blockIdx.x;
  int cpx = (gridDim.x * gridDim.y * gridDim.z) >> 3;   // grids are %8==0
  return (lid & 7) * cpx + (lid >> 3);
}

DEV f16x8 cvt8(float4 a, float4 b){
  f16x8 v;
  v[0]=(f16)a.x; v[1]=(f16)a.y; v[2]=(f16)a.z; v[3]=(f16)a.w;
  v[4]=(f16)b.x; v[5]=(f16)b.y; v[6]=(f16)b.z; v[7]=(f16)b.w;
  return v;
}

#define MFMA_(av, bv, ci, cj) \
  acc[ci][cj] = __builtin_amdgcn_mfma_f32_16x16x32_f16(av, bv, acc[ci][cj], 0, 0, 0)

// ================= R8 core (qk/pv): 8-phase, counted vmcnt =================
template<bool MORE>
DEV void ktile_body(const f16* (&src)[8], char* bufc, char* stash,
                    int ob0, int ob1, int rA, int rB, int sk0, int sk1,
                    f32x4 (&acc)[8][4])
{
  f16x8 a0[4], a1[4], b0[2], b1[2], b2[2], b3[2];

  // -------- phase 0 --------
  if (MORE){ gld_lds16(src[0], stash + 0 + ob0); src[0] += 64; }
  if (MORE) asm volatile("s_waitcnt vmcnt(5)\ns_barrier" ::: "memory");
  else      asm volatile("s_waitcnt vmcnt(4)\ns_barrier" ::: "memory");
#pragma unroll
  for (int i = 0; i < 4; i++) a0[i] = *(const f16x8*)(bufc + (i << 12) + rA + sk0);
  b0[0] = *(const f16x8*)(bufc + 32768 +    0 + rB + sk0);
  b0[1] = *(const f16x8*)(bufc + 32768 + 8192 + rB + sk0);
  __builtin_amdgcn_s_setprio(1);
#pragma unroll
  for (int i = 0; i < 4; i++){ MFMA_(a0[i], b0[0], i, 0); MFMA_(a0[i], b0[1], i, 1); }
  __builtin_amdgcn_s_setprio(0);

  // -------- phase 1 --------
  if (MORE){ gld_lds16(src[1], stash + 0 + ob1); src[1] += 64; }
#pragma unroll
  for (int i = 0; i < 4; i++) a1[i] = *(const f16x8*)(bufc + (i << 12) + rA + sk1);
  b1[0] = *(const f16x8*)(bufc + 32768 +    0 + rB + sk1);
  b1[1] = *(const f16x8*)(bufc + 32768 + 8192 + rB + sk1);
  __builtin_amdgcn_s_setprio(1);
#pragma unroll
  for (int i = 0; i < 4; i++){ MFMA_(a1[i], b1[0], i, 0); MFMA_(a1[i], b1[1], i, 1); }
  __builtin_amdgcn_s_setprio(0);

  // -------- phase 2 --------
  if (MORE){ gld_lds16(src[2], stash + 32768 + ob0); src[2] += 64; }
  if (MORE) asm volatile("s_waitcnt vmcnt(3)\ns_barrier" ::: "memory");
  else      asm volatile("s_waitcnt vmcnt(0)\ns_barrier" ::: "memory");
  b2[0] = *(const f16x8*)(bufc + 49152 +    0 + rB + sk0);
  b2[1] = *(const f16x8*)(bufc + 49152 + 8192 + rB + sk0);
  __builtin_amdgcn_s_setprio(1);
#pragma unroll
  for (int i = 0; i < 4; i++){ MFMA_(a0[i], b2[0], i, 2); MFMA_(a0[i], b2[1], i, 3); }
  __builtin_amdgcn_s_setprio(0);

  // -------- phase 3 --------
  if (MORE){ gld_lds16(src[3], stash + 32768 + ob1); src[3] += 64; }
  b3[0] = *(const f16x8*)(bufc + 49152 +    0 + rB + sk1);
  b3[1] = *(const f16x8*)(bufc + 49152 + 8192 + rB + sk1);
  __builtin_amdgcn_s_setprio(1);
#pragma unroll
  for (int i = 0; i < 4; i++){ MFMA_(a1[i], b3[0], i, 2); MFMA_(a1[i], b3[1], i, 3); }
  __builtin_amdgcn_s_setprio(0);

  // -------- phase 4 --------
  if (MORE){ gld_lds16(src[4], stash + 16384 + ob0); src[4] += 64; }
#pragma unroll
  for (int i = 0; i < 4; i++) a0[i] = *(const f16x8*)(bufc + 16384 + (i << 12) + rA + sk0);
  __builtin_amdgcn_s_setprio(1);
#pragma unroll
  for (int i = 0; i < 4; i++){ MFMA_(a0[i], b0[0], 4 + i, 0); MFMA_(a0[i], b0[1], 4 + i, 1); }
  __builtin_amdgcn_s_setprio(0);

  // -------- phase 5 --------
  if (MORE){ gld_lds16(src[5], stash + 16384 + ob1); src[5] += 64; }
#pragma unroll
  for (int i = 0; i < 4; i++) a1[i] = *(const f16x8*)(bufc + 16384 + (i << 12) + rA + sk1);
  __builtin_amdgcn_s_setprio(1);
#pragma unroll
  for (int i = 0; i < 4; i++){ MFMA_(a1[i], b1[0], 4 + i, 0); MFMA_(a1[i], b1[1], 4 + i, 1); }
  __builtin_amdgcn_s_setprio(0);

  // -------- phase 6 --------
  if (MORE){ gld_lds16(src[6], stash + 49152 + ob0); src[6] += 64; }
  __builtin_amdgcn_s_setprio(1);
#pragma unroll
  for (int i = 0; i < 4; i++){ MFMA_(a0[i], b2[0], 4 + i, 2); MFMA_(a0[i], b2[1], 4 + i, 3); }
  __builtin_amdgcn_s_setprio(0);

  // -------- phase 7 --------
  if (MORE){ gld_lds16(src[7], stash + 49152 + ob1); src[7] += 64; }
  __builtin_amdgcn_s_setprio(1);
#pragma unroll
  for (int i = 0; i < 4; i++){ MFMA_(a1[i], b3[0], 4 + i, 2); MFMA_(a1[i], b3[1], 4 + i, 3); }
  __builtin_amdgcn_s_setprio(0);
}

DEV void gemm_core(const f16* __restrict__ A, int lda,
                   const f16* __restrict__ B, int ldb,
                   int nt, char* smem, f32x4 (&acc)[8][4])
{
  const int tid  = threadIdx.x;
  const int lane = tid & 63;
  const int wv   = tid >> 6;
  const int wm   = wv >> 2, wn = wv & 3;
  const int lr   = lane & 15, lq = lane >> 4;

  const int ob0 = tid * 16;
  const int ob1 = ob0 + 8192;
  const int r0  = ob0 >> 7, r1 = ob1 >> 7;
  const int sl0 = ((ob0 >> 4) & 7) ^ (r0 & 7);
  const int sl1 = ((ob1 >> 4) & 7) ^ (r1 & 7);
  const f16* src[8];
  src[0] = A + (size_t)r0 * lda + sl0 * 8;
  src[1] = A + (size_t)r1 * lda + sl1 * 8;
  src[2] = B + (size_t)r0 * ldb + sl0 * 8;
  src[3] = B + (size_t)r1 * ldb + sl1 * 8;
  src[4] = A + (size_t)(128 + r0) * lda + sl0 * 8;
  src[5] = A + (size_t)(128 + r1) * lda + sl1 * 8;
  src[6] = B + (size_t)(128 + r0) * ldb + sl0 * 8;
  src[7] = B + (size_t)(128 + r1) * ldb + sl1 * 8;

  const int rA  = (wm * 16 + lr) << 7;
  const int rB  = (wn * 16 + lr) << 7;
  const int sk0 = ((lq ^ (lane & 7)) << 4);
  const int sk1 = (((4 | lq) ^ (lane & 7)) << 4);

#pragma unroll
  for (int i = 0; i < 8; i++)
#pragma unroll
    for (int j = 0; j < 4; j++) acc[i][j] = (f32x4){0.f, 0.f, 0.f, 0.f};

  gld_lds16(src[0], smem +     0 + ob0); src[0] += 64;
  gld_lds16(src[1], smem +     0 + ob1); src[1] += 64;
  gld_lds16(src[2], smem + 32768 + ob0); src[2] += 64;
  gld_lds16(src[3], smem + 32768 + ob1); src[3] += 64;
  gld_lds16(src[4], smem + 16384 + ob0); src[4] += 64;
  gld_lds16(src[5], smem + 16384 + ob1); src[5] += 64;
  gld_lds16(src[6], smem + 49152 + ob0); src[6] += 64;
  gld_lds16(src[7], smem + 49152 + ob1); src[7] += 64;

  for (int t = 0; t < nt - 1; ++t){
    char* bufc  = smem + ((t & 1) << 16);
    char* stash = smem + (((t & 1) ^ 1) << 16);
    ktile_body<true>(src, bufc, stash, ob0, ob1, rA, rB, sk0, sk1, acc);
  }
  {
    char* bufc  = smem + (((nt - 1) & 1) << 16);
    char* stash = smem + ((((nt - 1) & 1) ^ 1) << 16);
    ktile_body<false>(src, bufc, stash, ob0, ob1, rA, rB, sk0, sk1, acc);
  }
}

// ============ proj core: A reg-staged from fp32 (fused cvt), B gld_lds ============
// Per K-tile: p0 issue 4 A-h0 fp32 loads -> vmcnt(4)+lgkmcnt(0)+barrier (drains
// all 4 B gld_lds of tile t + ds_writes); p2 cvt+2 ds_write h0 + issue 4 B(t+1);
// p4 issue 4 A-h1 loads; p6 cvt+2 ds_write h1. ONE barrier per tile.
template<bool MORE>
DEV void ktile_proj(const float* (&srcA)[4], const f16* (&srcB)[4],
                    char* bufc, char* stash,
                    int ob0, int ob1, int rA, int rB, int sk0, int sk1,
                    f32x4 (&acc)[8][4])
{
  f16x8 a0[4], a1[4], b0[2], b1[2], b2[2], b3[2];
  float4 h0a, h0b, h1a, h1b;   // A(t+1) in-flight (reused for h0 then h1)
  float4 g0a, g0b, g1a, g1b;

  // -------- phase 0 --------
  if (MORE){
    h0a = *(const float4*)(srcA[0]); h0b = *(const float4*)(srcA[0] + 4);
    g0a = *(const float4*)(srcA[1]); g0b = *(const float4*)(srcA[1] + 4);
    srcA[0] += 64; srcA[1] += 64;
    asm volatile("s_waitcnt vmcnt(4) lgkmcnt(0)\ns_barrier" ::: "memory");
  } else {
    asm volatile("s_waitcnt vmcnt(0) lgkmcnt(0)\ns_barrier" ::: "memory");
  }
#pragma unroll
  for (int i = 0; i < 4; i++) a0[i] = *(const f16x8*)(bufc + (i << 12) + rA + sk0);
  b0[0] = *(const f16x8*)(bufc + 32768 +    0 + rB + sk0);
  b0[1] = *(const f16x8*)(bufc + 32768 + 8192 + rB + sk0);
  __builtin_amdgcn_s_setprio(1);
#pragma unroll
  for (int i = 0; i < 4; i++){ MFMA_(a0[i], b0[0], i, 0); MFMA_(a0[i], b0[1], i, 1); }
  __builtin_amdgcn_s_setprio(0);

  // -------- phase 1 --------
#pragma unroll
  for (int i = 0; i < 4; i++) a1[i] = *(const f16x8*)(bufc + (i << 12) + rA + sk1);
  b1[0] = *(const f16x8*)(bufc + 32768 +    0 + rB + sk1);
  b1[1] = *(const f16x8*)(bufc + 32768 + 8192 + rB + sk1);
  __builtin_amdgcn_s_setprio(1);
#pragma unroll
  for (int i = 0; i < 4; i++){ MFMA_(a1[i], b1[0], i, 0); MFMA_(a1[i], b1[1], i, 1); }
  __builtin_amdgcn_s_setprio(0);

  // -------- phase 2 -------- (stash-A writes legal: region idle since barrier)
  if (MORE){
    *(f16x8*)(stash + ob0) = cvt8(h0a, h0b);
    *(f16x8*)(stash + ob1) = cvt8(g0a, g0b);
    gld_lds16(srcB[0], stash + 32768 + ob0); srcB[0] += 64;
    gld_lds16(srcB[1], stash + 32768 + ob1); srcB[1] += 64;
    gld_lds16(srcB[2], stash + 49152 + ob0); srcB[2] += 64;
    gld_lds16(srcB[3], stash + 49152 + ob1); srcB[3] += 64;
  }
  b2[0] = *(const f16x8*)(bufc + 49152 +    0 + rB + sk0);
  b2[1] = *(const f16x8*)(bufc + 49152 + 8192 + rB + sk0);
  __builtin_amdgcn_s_setprio(1);
#pragma unroll
  for (int i = 0; i < 4; i++){ MFMA_(a0[i], b2[0], i, 2); MFMA_(a0[i], b2[1], i, 3); }
  __builtin_amdgcn_s_setprio(0);

  // -------- phase 3 --------
  b3[0] = *(const f16x8*)(bufc + 49152 +    0 + rB + sk1);
  b3[1] = *(const f16x8*)(bufc + 49152 + 8192 + rB + sk1);
  __builtin_amdgcn_s_setprio(1);
#pragma unroll
  for (int i = 0; i < 4; i++){ MFMA_(a1[i], b3[0], i, 2); MFMA_(a1[i], b3[1], i, 3); }
  __builtin_amdgcn_s_setprio(0);

  // -------- phase 4 --------
  if (MORE){
    h1a = *(const float4*)(srcA[2]); h1b = *(const float4*)(srcA[2] + 4);
    g1a = *(const float4*)(srcA[3]); g1b = *(const float4*)(srcA[3] + 4);
    srcA[2] += 64; srcA[3] += 64;
  }
#pragma unroll
  for (int i = 0; i < 4; i++) a0[i] = *(const f16x8*)(bufc + 16384 + (i << 12) + rA + sk0);
  __builtin_amdgcn_s_setprio(1);
#pragma unroll
  for (int i = 0; i < 4; i++){ MFMA_(a0[i], b0[0], 4 + i, 0); MFMA_(a0[i], b0[1], 4 + i, 1); }
  __builtin_amdgcn_s_setprio(0);

  // -------- phase 5 --------
#pragma unroll
  for (int i = 0; i < 4; i++) a1[i] = *(const f16x8*)(bufc + 16384 + (i << 12) + rA + sk1);
  __builtin_amdgcn_s_setprio(1);
#pragma unroll
  for (int i = 0; i < 4; i++){ MFMA_(a1[i], b1[0], 4 + i, 0); MFMA_(a1[i], b1[1], 4 + i, 1); }
  __builtin_amdgcn_s_setprio(0);

  // -------- phase 6 --------
  if (MORE){
    *(f16x8*)(stash + 16384 + ob0) = cvt8(h1a, h1b);
    *(f16x8*)(stash + 16384 + ob1) = cvt8(g1a, g1b);
  }
  __builtin_amdgcn_s_setprio(1);
#pragma unroll
  for (int i = 0; i < 4; i++){ MFMA_(a0[i], b2[0], 4 + i, 2); MFMA_(a0[i], b2[1], 4 + i, 3); }
  __builtin_amdgcn_s_setprio(0);

  // -------- phase 7 --------
  __builtin_amdgcn_s_setprio(1);
#pragma unroll
  for (int i = 0; i < 4; i++){ MFMA_(a1[i], b3[0], 4 + i, 2); MFMA_(a1[i], b3[1], 4 + i, 3); }
  __builtin_amdgcn_s_setprio(0);
}

DEV void gemm_core_proj(const float* __restrict__ A, int lda,
                        const f16* __restrict__ B, int ldb,
                        int nt, char* smem, f32x4 (&acc)[8][4])
{
  const int tid  = threadIdx.x;
  const int lane = tid & 63;
  const int wv   = tid >> 6;
  const int wm   = wv >> 2, wn = wv & 3;
  const int lr   = lane & 15, lq = lane >> 4;

  const int ob0 = tid * 16;
  const int ob1 = ob0 + 8192;
  const int r0  = ob0 >> 7, r1 = ob1 >> 7;
  const int sl0 = ((ob0 >> 4) & 7) ^ (r0 & 7);
  const int sl1 = ((ob1 >> 4) & 7) ^ (r1 & 7);
  const float* srcA[4];
  srcA[0] = A + (size_t)r0 * lda + sl0 * 8;
  srcA[1] = A + (size_t)r1 * lda + sl1 * 8;
  srcA[2] = A + (size_t)(128 + r0) * lda + sl0 * 8;
  srcA[3] = A + (size_t)(128 + r1) * lda + sl1 * 8;
  const f16* srcB[4];
  srcB[0] = B + (size_t)r0 * ldb + sl0 * 8;
  srcB[1] = B + (size_t)r1 * ldb + sl1 * 8;
  srcB[2] = B + (size_t)(128 + r0) * ldb + sl0 * 8;
  srcB[3] = B + (size_t)(128 + r1) * ldb + sl1 * 8;

  const int rA  = (wm * 16 + lr) << 7;
  const int rB  = (wn * 16 + lr) << 7;
  const int sk0 = ((lq ^ (lane & 7)) << 4);
  const int sk1 = (((4 | lq) ^ (lane & 7)) << 4);

#pragma unroll
  for (int i = 0; i < 8; i++)
#pragma unroll
    for (int j = 0; j < 4; j++) acc[i][j] = (f32x4){0.f, 0.f, 0.f, 0.f};

  // prologue: reg-stage A(0) (fp32->f16), gld_lds B(0)
  {
    float4 a0 = *(const float4*)(srcA[0]), a0h = *(const float4*)(srcA[0] + 4);
    float4 a1 = *(const float4*)(srcA[1]), a1h = *(const float4*)(srcA[1] + 4);
    float4 a2 = *(const float4*)(srcA[2]), a2h = *(const float4*)(srcA[2] + 4);
    float4 a3 = *(const float4*)(srcA[3]), a3h = *(const float4*)(srcA[3] + 4);
    srcA[0] += 64; srcA[1] += 64; srcA[2] += 64; srcA[3] += 64;
    *(f16x8*)(smem +         ob0) = cvt8(a0, a0h);
    *(f16x8*)(smem +         ob1) = cvt8(a1, a1h);
    *(f16x8*)(smem + 16384 + ob0) = cvt8(a2, a2h);
    *(f16x8*)(smem + 16384 + ob1) = cvt8(a3, a3h);
  }
  gld_lds16(srcB[0], smem + 32768 + ob0); srcB[0] += 64;
  gld_lds16(srcB[1], smem + 32768 + ob1); srcB[1] += 64;
  gld_lds16(srcB[2], smem + 49152 + ob0); srcB[2] += 64;
  gld_lds16(srcB[3], smem + 49152 + ob1); srcB[3] += 64;

  for (int t = 0; t < nt - 1; ++t){
    char* bufc  = smem + ((t & 1) << 16);
    char* stash = smem + (((t & 1) ^ 1) << 16);
    ktile_proj<true>(srcA, srcB, bufc, stash, ob0, ob1, rA, rB, sk0, sk1, acc);
  }
  {
    char* bufc  = smem + (((nt - 1) & 1) << 16);
    char* stash = smem + ((((nt - 1) & 1) ^ 1) << 16);
    ktile_proj<false>(srcA, srcB, bufc, stash, ob0, ob1, rA, rB, sk0, sk1, acc);
  }
}

// ---------------- fused Q/K/V projections (fp32 inputs, fused cvt) ----------------
__global__ __launch_bounds__(512, 2) void proj8p(
    const float* __restrict__ xq, const float* __restrict__ xk, const float* __restrict__ xv,
    const f16* __restrict__ wq, const f16* __restrict__ wk, const f16* __restrict__ wv,
    const float* __restrict__ bq, const float* __restrict__ bk, const float* __restrict__ bv,
    f16* __restrict__ oq, f16* __restrict__ ok, f16* __restrict__ ovT)
{
  __shared__ char smem[131072];
  const int s  = swz_lid();               // grid (4, 32, 3)
  const int bx = s & 3, by = (s >> 2) & 31, z = s >> 7;
  const int m0 = by * 256, n0 = bx * 256;
  const float* A = (z == 0 ? xq : z == 1 ? xk : xv) + (size_t)m0 * 1024;
  const f16*   B = (z == 0 ? wq : z == 1 ? wk : wv) + (size_t)n0 * 1024;
  const float* bias = (z == 0 ? bq : z == 1 ? bk : bv);

  f32x4 acc[8][4];
  gemm_core_proj(A, 1024, B, 1024, 16, smem, acc);

  const int lane = threadIdx.x & 63;
  const int wv_  = threadIdx.x >> 6;
  const int wm = wv_ >> 2, wn = wv_ & 3;
  const int lr = lane & 15, rj = (lane >> 4) * 4;

  if (z < 2){
    f16* o = z ? ok : oq;
#pragma unroll
    for (int i = 0; i < 8; i++)
#pragma unroll
      for (int j = 0; j < 4; j++){
        int row = m0 + i * 32 + wm * 16 + rj;
        int col = n0 + j * 64 + wn * 16 + lr;
        float bvl = bias[col];
#pragma unroll
        for (int r = 0; r < 4; r++)
          o[(size_t)(row + r) * 1024 + col] = (f16)(acc[i][j][r] + bvl);
      }
  } else { // V: transposed fp16 -> ovT[feature][8192 tokens]
#pragma unroll
    for (int i = 0; i < 8; i++)
#pragma unroll
      for (int j = 0; j < 4; j++){
        int row = m0 + i * 32 + wm * 16 + rj;
        int col = n0 + j * 64 + wn * 16 + lr;
        float bvl = bias[col];
        f16x4 tv;
#pragma unroll
        for (int r = 0; r < 4; r++) tv[r] = (f16)(acc[i][j][r] + bvl);
        *(f16x4*)(ovT + (size_t)col * 8192 + row) = tv;
      }
  }
}

// ---------------- QK^T (per batch, fp32 logits) -- exact R8 ----------------
__global__ __launch_bounds__(512, 2) void qk8p(
    const f16* __restrict__ q, const f16* __restrict__ k, float* __restrict__ Sout)
{
  __shared__ char smem[131072];
  const int s  = swz_lid();               // grid (8, 8, 4)
  const int bx = s & 7, by = (s >> 3) & 7, z = s >> 6;
  const int m0 = by * 256, n0 = bx * 256;
  const f16* A = q + (size_t)z * 2048 * 1024 + (size_t)m0 * 1024;
  const f16* B = k + (size_t)z * 2048 * 1024 + (size_t)n0 * 1024;

  f32x4 acc[8][4];
  gemm_core(A, 1024, B, 1024, 16, smem, acc);

  const int lane = threadIdx.x & 63;
  const int wv_  = threadIdx.x >> 6;
  const int wm = wv_ >> 2, wn = wv_ & 3;
  const int lr = lane & 15, rj = (lane >> 4) * 4;
  float* o = Sout + (size_t)z * 2048 * 2048;
#pragma unroll
  for (int i = 0; i < 8; i++)
#pragma unroll
    for (int j = 0; j < 4; j++){
      int row = m0 + i * 32 + wm * 16 + rj;
      int col = n0 + j * 64 + wn * 16 + lr;
#pragma unroll
      for (int r = 0; r < 4; r++)
        o[(size_t)(row + r) * 2048 + col] = acc[i][j][r];
    }
}

// ---------------- PV (per batch, split-K x2 -> f16 partials) -- exact R8 ----------------
__global__ __launch_bounds__(512, 2) void pv8p(
    const f16* __restrict__ P, const f16* __restrict__ vT, f16* __restrict__ O)
{
  __shared__ char smem[131072];
  const int s  = swz_lid();               // grid (4, 8, 8)
  const int bx = s & 3, by = (s >> 2) & 7, z = s >> 5;
  const int zb = z >> 1, h = z & 1;
  const int m0 = by * 256, n0 = bx * 256;
  const f16* A = P  + (size_t)zb * 2048 * 2048 + (size_t)m0 * 2048 + h * 1024;
  const f16* B = vT + (size_t)n0 * 8192 + (size_t)zb * 2048 + h * 1024;

  f32x4 acc[8][4];
  gemm_core(A, 2048, B, 8192, 16, smem, acc);

  const int lane = threadIdx.x & 63;
  const int wv_  = threadIdx.x >> 6;
  const int wm = wv_ >> 2, wn = wv_ & 3;
  const int lr = lane & 15, rj = (lane >> 4) * 4;
  f16* o = O + (size_t)h * 8388608 + (size_t)zb * 2048 * 1024;
#pragma unroll
  for (int i = 0; i < 8; i++)
#pragma unroll
    for (int j = 0; j < 4; j++){
      int row = m0 + i * 32 + wm * 16 + rj;
      int col = n0 + j * 64 + wn * 16 + lr;
#pragma unroll
      for (int r = 0; r < 4; r++)
        o[(size_t)(row + r) * 1024 + col] = (f16)acc[i][j][r];
    }
}

// ------------- W [d][f] fp32 -> Wt [f][d] fp16, 3 weights in one launch -------------
__global__ __launch_bounds__(256) void transpose3_cvt_w(
    const float* __restrict__ W0, const float* __restrict__ W1, const float* __restrict__ W2,
    f16* __restrict__ T0, f16* __restrict__ T1, f16* __restrict__ T2, int D){
  const int z = blockIdx.z;
  const float* W = z == 0 ? W0 : z == 1 ? W1 : W2;
  f16* T = z == 0 ? T0 : z == 1 ? T1 : T2;
  __shared__ float t[32][33];
  int tx = threadIdx.x & 31, ty = threadIdx.x >> 5; // 32 x 8
  int bx = blockIdx.x * 32, by = blockIdx.y * 32;
#pragma unroll
  for (int j = 0; j < 4; j++) t[ty + j*8][tx] = W[(size_t)(by + ty + j*8) * D + bx + tx];
  __syncthreads();
#pragma unroll
  for (int j = 0; j < 4; j++){
    float v = t[tx][ty + j*8];
    T[(size_t)(bx + ty + j*8) * D + by + tx] = (f16)v;
  }
}

// ---------------- row softmax, wave-per-row: S fp32 [8192][2048] -> P f16 ----
__global__ __launch_bounds__(256) void softmax_rows(const float* __restrict__ S, f16* __restrict__ P){
  const int row  = blockIdx.x * 4 + (threadIdx.x >> 6);
  const int lane = threadIdx.x & 63;
  const float* x = S + (size_t)row * 2048 + lane * 32;
  float v[32];
  float m = -3.4e38f;
#pragma unroll
  for (int c = 0; c < 8; c++){
    float4 t = *(const float4*)(x + c * 4);
    v[c*4+0] = t.x; v[c*4+1] = t.y; v[c*4+2] = t.z; v[c*4+3] = t.w;
    m = fmaxf(m, fmaxf(fmaxf(t.x, t.y), fmaxf(t.z, t.w)));
  }
#pragma unroll
  for (int o = 32; o; o >>= 1) m = fmaxf(m, __shfl_xor(m, o));
  float ssum = 0.f;
#pragma unroll
  for (int j = 0; j < 32; j++){ v[j] = __expf(v[j] - m); ssum += v[j]; }
#pragma unroll
  for (int o = 32; o; o >>= 1) ssum += __shfl_xor(ssum, o);
  float inv = 1.f / ssum;
  f16* p = P + (size_t)row * 2048 + lane * 32;
#pragma unroll
  for (int c = 0; c < 4; c++){
    f16x8 ov;
#pragma unroll
    for (int j = 0; j < 8; j++) ov[j] = (f16)(v[c*8+j] * inv);
    *(f16x8*)(p + c * 8) = ov;
  }
}

// ---------------- residual + layernorm (sums two f16 partials) ----------------
DEV float wred_sum(float v){
#pragma unroll
  for (int o = 32; o; o >>= 1) v += __shfl_xor(v, o);
  return v;
}

__global__ __launch_bounds__(256) void resid_ln2(const f16* __restrict__ O0,
                                                 const f16* __restrict__ O1,
                                                 const float* __restrict__ query,
                                                 const float* __restrict__ gamma,
                                                 const float* __restrict__ beta,
                                                 float* __restrict__ out){
  const int row = blockIdx.x;
  const int tid = threadIdx.x;
  const size_t base = (size_t)row * 1024 + tid * 4;
  f16x4 o4 = *(const f16x4*)(O0 + base);
  f16x4 p4 = *(const f16x4*)(O1 + base);
  float4 q4 = *(const float4*)(query + base);
  float x[4] = {(float)o4[0] + (float)p4[0] + q4.x,
                (float)o4[1] + (float)p4[1] + q4.y,
                (float)o4[2] + (float)p4[2] + q4.z,
                (float)o4[3] + (float)p4[3] + q4.w};
  float s = 0.f, ss = 0.f;
#pragma unroll
  for (int j = 0; j < 4; j++){ s += x[j]; ss += x[j] * x[j]; }

  __shared__ float red[4];
  s = wred_sum(s);
  if ((tid & 63) == 0) red[tid >> 6] = s;
  __syncthreads();
  s = red[0] + red[1] + red[2] + red[3];
  ss = wred_sum(ss);
  __syncthreads();
  if ((tid & 63) == 0) red[tid >> 6] = ss;
  __syncthreads();
  ss = red[0] + red[1] + red[2] + red[3];

  float mu = s * (1.f / 1024.f);
  float var = ss * (1.f / 1024.f) - mu * mu;
  float rs = rsqrtf(var + 1e-5f);
  float4 g4 = *(const float4*)(gamma + tid * 4);
  float4 b4 = *(const float4*)(beta + tid * 4);
  float4 r;
  r.x = (x[0] - mu) * rs * g4.x + b4.x;
  r.y = (x[1] - mu) * rs * g4.y + b4.y;
  r.z = (x[2] - mu) * rs * g4.z + b4.z;
  r.w = (x[3] - mu) * rs * g4.w + b4.w;
  *(float4*)(out + base) = r;
}

// ---------------- launch ----------------
extern "C" void kernel_launch(void* const* d_in, const int* in_sizes, int n_in,
                              void* d_out, int out_size, void* d_ws, size_t ws_size,
                              hipStream_t stream){
  const float* query  = (const float*)d_in[0];
  const float* key_in = (const float*)d_in[1];
  const float* value  = (const float*)d_in[2];
  const float* Wq = (const float*)d_in[3];
  const float* bq = (const float*)d_in[4];
  const float* Wk = (const float*)d_in[5];
  const float* bk = (const float*)d_in[6];
  const float* Wv = (const float*)d_in[7];
  const float* bv = (const float*)d_in[8];
  const float* gamma = (const float*)d_in[9];
  const float* beta  = (const float*)d_in[10];

  const int B = 4, S = 2048, D = 1024;
  const int M = B * S;                 // 8192 tokens
  const size_t MB = 1ull << 20;
  char* ws = (char*)d_ws;

  f16* qf16 = (f16*)(ws + 0);
  f16* kf16 = (f16*)(ws + 16 * MB);
  f16* vT   = (f16*)(ws + 32 * MB);    // [1024][8192]
  f16* wt_q = (f16*)(ws + 48 * MB);
  f16* wt_k = (f16*)(ws + 50 * MB);
  f16* wt_v = (f16*)(ws + 52 * MB);
  f16* Obuf = (f16*)(ws + 54 * MB);    // O0 @54, O1 @70 (16MB each, f16)
  float* Sbuf = (float*)(ws + 118 * MB);  // 64MB
  f16*   Pbuf = (f16*)(ws + 182 * MB);    // 32MB

  dim3 blk(256);

  transpose3_cvt_w<<<dim3(32, 32, 3), blk, 0, stream>>>(Wq, Wk, Wv, wt_q, wt_k, wt_v, D);

  // fused projections (reads fp32 inputs directly): grid (4, 32, 3)
  proj8p<<<dim3(4, 32, 3), dim3(512), 0, stream>>>(query, key_in, value,
                                                   wt_q, wt_k, wt_v,
                                                   bq, bk, bv, qf16, kf16, vT);

  // QK^T per batch: 256 WGs
  qk8p<<<dim3(8, 8, 4), dim3(512), 0, stream>>>(qf16, kf16, Sbuf);

  // wave-per-row softmax: 4 rows/block
  softmax_rows<<<M / 4, blk, 0, stream>>>(Sbuf, Pbuf);

  // PV per batch, split-K x2: 256 WGs, f16 partials
  pv8p<<<dim3(4, 8, 8), dim3(512), 0, stream>>>(Pbuf, vT, Obuf);

  resid_ln2<<<M, blk, 0, stream>>>(Obuf, Obuf + 8388608, query, gamma, beta, (float*)d_out);
}

// Round 12
// 192.658 us; speedup vs baseline: 1.1117x; 1.1117x over previous
//
#include <hip/hip_runtime.h>
#include <hip/hip_bf16.h>
#include <cstdint>

// SelfAttention fused pipeline, MI355X gfx950. Round 12: compose winners.
//  proj: R10 core (128x256, BK=32, 48KB LDS, 4 waves/SIMD, 768 WGs = 3 exact
//        rounds) -- benched 69us.
//  qk/pv: R8 core (256^2, 8-phase counted vmcnt, 128KB LDS) -- benched best.
//  cvt3/transpose3/softmax/LN: R8 exact (all at HBM roofline).
// B=4, S=2048, D=1024. fp32 in/out; fp16 MFMA internally.
//
// ws layout (MB offsets): 0 qf16(16) | 16 kf16(16) | 32 vT(16) | 48/50/52 wt
// | 54 O0 f16(16) | 70 O1 f16(16) | 118 xq(16) | 134 xk(16) | 150 xv(16)
// | 118 Sbuf fp32(64, aliases xq..xv after proj) | 182 Pbuf f16(32).

typedef unsigned short u16;
typedef unsigned int   u32;
typedef _Float16 f16;
typedef f16   f16x8  __attribute__((ext_vector_type(8)));
typedef f16   f16x4  __attribute__((ext_vector_type(4)));
typedef float f32x4  __attribute__((ext_vector_type(4)));

#define DEV __device__ __forceinline__

DEV void gld_lds16(const f16* g, char* l){
  __builtin_amdgcn_global_load_lds(
      (const __attribute__((address_space(1))) u32*)(uintptr_t)g,
      (__attribute__((address_space(3))) u32*)(u32)(uintptr_t)l, 16, 0, 0);
}

// T1: bijective XCD-contiguous remap of the linearized block id.
DEV int swz_lid(){
  int lid = (blockIdx.z * gridDim.y + blockIdx.y) * gridDim.x + blockIdx.x;
  int cpx = (gridDim.x * gridDim.y * gridDim.z) >> 3;   // grids are %8==0
  return (lid & 7) * cpx + (lid >> 3);
}

#define MFMA_(av, bv, ci, cj) \
  acc[ci][cj] = __builtin_amdgcn_mfma_f32_16x16x32_f16(av, bv, acc[ci][cj], 0, 0, 0)

// ================= R8 core (qk/pv): 256^2, 8-phase, counted vmcnt =================
template<bool MORE>
DEV void ktile_body(const f16* (&src)[8], char* bufc, char* stash,
                    int ob0, int ob1, int rA, int rB, int sk0, int sk1,
                    f32x4 (&acc)[8][4])
{
  f16x8 a0[4], a1[4], b0[2], b1[2], b2[2], b3[2];

  // -------- phase 0 --------
  if (MORE){ gld_lds16(src[0], stash + 0 + ob0); src[0] += 64; }
  if (MORE) asm volatile("s_waitcnt vmcnt(5)\ns_barrier" ::: "memory");
  else      asm volatile("s_waitcnt vmcnt(4)\ns_barrier" ::: "memory");
#pragma unroll
  for (int i = 0; i < 4; i++) a0[i] = *(const f16x8*)(bufc + (i << 12) + rA + sk0);
  b0[0] = *(const f16x8*)(bufc + 32768 +    0 + rB + sk0);
  b0[1] = *(const f16x8*)(bufc + 32768 + 8192 + rB + sk0);
  __builtin_amdgcn_s_setprio(1);
#pragma unroll
  for (int i = 0; i < 4; i++){ MFMA_(a0[i], b0[0], i, 0); MFMA_(a0[i], b0[1], i, 1); }
  __builtin_amdgcn_s_setprio(0);

  // -------- phase 1 --------
  if (MORE){ gld_lds16(src[1], stash + 0 + ob1); src[1] += 64; }
#pragma unroll
  for (int i = 0; i < 4; i++) a1[i] = *(const f16x8*)(bufc + (i << 12) + rA + sk1);
  b1[0] = *(const f16x8*)(bufc + 32768 +    0 + rB + sk1);
  b1[1] = *(const f16x8*)(bufc + 32768 + 8192 + rB + sk1);
  __builtin_amdgcn_s_setprio(1);
#pragma unroll
  for (int i = 0; i < 4; i++){ MFMA_(a1[i], b1[0], i, 0); MFMA_(a1[i], b1[1], i, 1); }
  __builtin_amdgcn_s_setprio(0);

  // -------- phase 2 --------
  if (MORE){ gld_lds16(src[2], stash + 32768 + ob0); src[2] += 64; }
  if (MORE) asm volatile("s_waitcnt vmcnt(3)\ns_barrier" ::: "memory");
  else      asm volatile("s_waitcnt vmcnt(0)\ns_barrier" ::: "memory");
  b2[0] = *(const f16x8*)(bufc + 49152 +    0 + rB + sk0);
  b2[1] = *(const f16x8*)(bufc + 49152 + 8192 + rB + sk0);
  __builtin_amdgcn_s_setprio(1);
#pragma unroll
  for (int i = 0; i < 4; i++){ MFMA_(a0[i], b2[0], i, 2); MFMA_(a0[i], b2[1], i, 3); }
  __builtin_amdgcn_s_setprio(0);

  // -------- phase 3 --------
  if (MORE){ gld_lds16(src[3], stash + 32768 + ob1); src[3] += 64; }
  b3[0] = *(const f16x8*)(bufc + 49152 +    0 + rB + sk1);
  b3[1] = *(const f16x8*)(bufc + 49152 + 8192 + rB + sk1);
  __builtin_amdgcn_s_setprio(1);
#pragma unroll
  for (int i = 0; i < 4; i++){ MFMA_(a1[i], b3[0], i, 2); MFMA_(a1[i], b3[1], i, 3); }
  __builtin_amdgcn_s_setprio(0);

  // -------- phase 4 --------
  if (MORE){ gld_lds16(src[4], stash + 16384 + ob0); src[4] += 64; }
#pragma unroll
  for (int i = 0; i < 4; i++) a0[i] = *(const f16x8*)(bufc + 16384 + (i << 12) + rA + sk0);
  __builtin_amdgcn_s_setprio(1);
#pragma unroll
  for (int i = 0; i < 4; i++){ MFMA_(a0[i], b0[0], 4 + i, 0); MFMA_(a0[i], b0[1], 4 + i, 1); }
  __builtin_amdgcn_s_setprio(0);

  // -------- phase 5 --------
  if (MORE){ gld_lds16(src[5], stash + 16384 + ob1); src[5] += 64; }
#pragma unroll
  for (int i = 0; i < 4; i++) a1[i] = *(const f16x8*)(bufc + 16384 + (i << 12) + rA + sk1);
  __builtin_amdgcn_s_setprio(1);
#pragma unroll
  for (int i = 0; i < 4; i++){ MFMA_(a1[i], b1[0], 4 + i, 0); MFMA_(a1[i], b1[1], 4 + i, 1); }
  __builtin_amdgcn_s_setprio(0);

  // -------- phase 6 --------
  if (MORE){ gld_lds16(src[6], stash + 49152 + ob0); src[6] += 64; }
  __builtin_amdgcn_s_setprio(1);
#pragma unroll
  for (int i = 0; i < 4; i++){ MFMA_(a0[i], b2[0], 4 + i, 2); MFMA_(a0[i], b2[1], 4 + i, 3); }
  __builtin_amdgcn_s_setprio(0);

  // -------- phase 7 --------
  if (MORE){ gld_lds16(src[7], stash + 49152 + ob1); src[7] += 64; }
  __builtin_amdgcn_s_setprio(1);
#pragma unroll
  for (int i = 0; i < 4; i++){ MFMA_(a1[i], b3[0], 4 + i, 2); MFMA_(a1[i], b3[1], 4 + i, 3); }
  __builtin_amdgcn_s_setprio(0);
}

DEV void gemm_core(const f16* __restrict__ A, int lda,
                   const f16* __restrict__ B, int ldb,
                   int nt, char* smem, f32x4 (&acc)[8][4])
{
  const int tid  = threadIdx.x;
  const int lane = tid & 63;
  const int wv   = tid >> 6;
  const int wm   = wv >> 2, wn = wv & 3;
  const int lr   = lane & 15, lq = lane >> 4;

  const int ob0 = tid * 16;
  const int ob1 = ob0 + 8192;
  const int r0  = ob0 >> 7, r1 = ob1 >> 7;
  const int sl0 = ((ob0 >> 4) & 7) ^ (r0 & 7);
  const int sl1 = ((ob1 >> 4) & 7) ^ (r1 & 7);
  const f16* src[8];
  src[0] = A + (size_t)r0 * lda + sl0 * 8;
  src[1] = A + (size_t)r1 * lda + sl1 * 8;
  src[2] = B + (size_t)r0 * ldb + sl0 * 8;
  src[3] = B + (size_t)r1 * ldb + sl1 * 8;
  src[4] = A + (size_t)(128 + r0) * lda + sl0 * 8;
  src[5] = A + (size_t)(128 + r1) * lda + sl1 * 8;
  src[6] = B + (size_t)(128 + r0) * ldb + sl0 * 8;
  src[7] = B + (size_t)(128 + r1) * ldb + sl1 * 8;

  const int rA  = (wm * 16 + lr) << 7;
  const int rB  = (wn * 16 + lr) << 7;
  const int sk0 = ((lq ^ (lane & 7)) << 4);
  const int sk1 = (((4 | lq) ^ (lane & 7)) << 4);

#pragma unroll
  for (int i = 0; i < 8; i++)
#pragma unroll
    for (int j = 0; j < 4; j++) acc[i][j] = (f32x4){0.f, 0.f, 0.f, 0.f};

  gld_lds16(src[0], smem +     0 + ob0); src[0] += 64;
  gld_lds16(src[1], smem +     0 + ob1); src[1] += 64;
  gld_lds16(src[2], smem + 32768 + ob0); src[2] += 64;
  gld_lds16(src[3], smem + 32768 + ob1); src[3] += 64;
  gld_lds16(src[4], smem + 16384 + ob0); src[4] += 64;
  gld_lds16(src[5], smem + 16384 + ob1); src[5] += 64;
  gld_lds16(src[6], smem + 49152 + ob0); src[6] += 64;
  gld_lds16(src[7], smem + 49152 + ob1); src[7] += 64;

  for (int t = 0; t < nt - 1; ++t){
    char* bufc  = smem + ((t & 1) << 16);
    char* stash = smem + (((t & 1) ^ 1) << 16);
    ktile_body<true>(src, bufc, stash, ob0, ob1, rA, rB, sk0, sk1, acc);
  }
  {
    char* bufc  = smem + (((nt - 1) & 1) << 16);
    char* stash = smem + ((((nt - 1) & 1) ^ 1) << 16);
    ktile_body<false>(src, bufc, stash, ob0, ob1, rA, rB, sk0, sk1, acc);
  }
}

// ================= R10 core (proj): 128x256, BK=32, 4 waves/SIMD =================
template<bool MORE>
DEV void ktile_p(const f16* (&src)[3], char* bufc, char* stash,
                 int o, int aoff, int boff, f32x4 (&acc)[4][4])
{
  if (MORE){
    gld_lds16(src[0], stash +         o); src[0] += 32;   // A rows 0..127
    gld_lds16(src[1], stash +  8192 + o); src[1] += 32;   // B rows 0..127
    gld_lds16(src[2], stash + 16384 + o); src[2] += 32;   // B rows 128..255
    asm volatile("s_waitcnt vmcnt(3)\ns_barrier" ::: "memory");
  } else {
    asm volatile("s_waitcnt vmcnt(0)\ns_barrier" ::: "memory");
  }
  f16x8 a[4], b[4];
#pragma unroll
  for (int i = 0; i < 4; i++) a[i] = *(const f16x8*)(bufc + aoff + i * 1024);
#pragma unroll
  for (int j = 0; j < 4; j++) b[j] = *(const f16x8*)(bufc + boff + j * 1024);
  __builtin_amdgcn_s_setprio(1);
#pragma unroll
  for (int i = 0; i < 4; i++)
#pragma unroll
    for (int j = 0; j < 4; j++) MFMA_(a[i], b[j], i, j);
  __builtin_amdgcn_s_setprio(0);
  __builtin_amdgcn_sched_barrier(0);
  __builtin_amdgcn_s_barrier();
}

DEV void gemm_core_p(const f16* __restrict__ A, int lda,
                     const f16* __restrict__ B, size_t ldb,
                     int nt, char* smem, f32x4 (&acc)[4][4])
{
  const int tid  = threadIdx.x;
  const int lane = tid & 63;
  const int wv   = tid >> 6;          // 8 waves: 2 (wm) x 4 (wn)
  const int wm   = wv >> 2, wn = wv & 3;
  const int lr   = lane & 15, lq = lane >> 4;

  const int o  = tid * 16;
  const int r0 = o >> 6;                              // row 0..127
  const int sl = ((o >> 4) & 3) ^ ((r0 >> 1) & 3);    // pre-swizzled source
  const f16* src[3];
  src[0] = A + (size_t)r0 * lda + sl * 8;
  src[1] = B + (size_t)r0 * ldb + sl * 8;
  src[2] = B + (size_t)(128 + r0) * ldb + sl * 8;

  const int sw   = (lr >> 1) & 3;
  const int aoff =        (wm * 64 + lr) * 64 + ((lq ^ sw) << 4);
  const int boff = 8192 + (wn * 64 + lr) * 64 + ((lq ^ sw) << 4);

#pragma unroll
  for (int i = 0; i < 4; i++)
#pragma unroll
    for (int j = 0; j < 4; j++) acc[i][j] = (f32x4){0.f, 0.f, 0.f, 0.f};

  gld_lds16(src[0], smem +         o); src[0] += 32;
  gld_lds16(src[1], smem +  8192 + o); src[1] += 32;
  gld_lds16(src[2], smem + 16384 + o); src[2] += 32;

  for (int t = 0; t < nt - 1; ++t){
    char* bufc  = smem + (t & 1) * 24576;
    char* stash = smem + ((t & 1) ^ 1) * 24576;
    ktile_p<true>(src, bufc, stash, o, aoff, boff, acc);
  }
  {
    char* bufc  = smem + ((nt - 1) & 1) * 24576;
    char* stash = smem + (((nt - 1) & 1) ^ 1) * 24576;
    ktile_p<false>(src, bufc, stash, o, aoff, boff, acc);
  }
}

// ---------------- fused Q/K/V projections (R10 structure) ----------------
__global__ __launch_bounds__(512, 4) void proj8p(
    const f16* __restrict__ xq, const f16* __restrict__ xk, const f16* __restrict__ xv,
    const f16* __restrict__ wq, const f16* __restrict__ wk, const f16* __restrict__ wv,
    const float* __restrict__ bq, const float* __restrict__ bk, const float* __restrict__ bv,
    f16* __restrict__ oq, f16* __restrict__ ok, f16* __restrict__ ovT)
{
  __shared__ char smem[49152];
  const int s  = swz_lid();               // grid (4, 64, 3) = 768
  const int bx = s & 3, by = (s >> 2) & 63, z = s >> 8;
  const int m0 = by * 128, n0 = bx * 256;
  const f16* A = (z == 0 ? xq : z == 1 ? xk : xv) + (size_t)m0 * 1024;
  const f16* B = (z == 0 ? wq : z == 1 ? wk : wv) + (size_t)n0 * 1024;
  const float* bias = (z == 0 ? bq : z == 1 ? bk : bv);

  f32x4 acc[4][4];
  gemm_core_p(A, 1024, B, 1024, 32, smem, acc);

  const int lane = threadIdx.x & 63;
  const int wv_  = threadIdx.x >> 6;
  const int wm = wv_ >> 2, wn = wv_ & 3;
  const int lr = lane & 15, rj = (lane >> 4) * 4;

  if (z < 2){
    f16* o = z ? ok : oq;
#pragma unroll
    for (int i = 0; i < 4; i++)
#pragma unroll
      for (int j = 0; j < 4; j++){
        int row = m0 + wm * 64 + i * 16 + rj;
        int col = n0 + wn * 64 + j * 16 + lr;
        float bvl = bias[col];
#pragma unroll
        for (int r = 0; r < 4; r++)
          o[(size_t)(row + r) * 1024 + col] = (f16)(acc[i][j][r] + bvl);
      }
  } else { // V: transposed fp16 -> ovT[feature][8192 tokens]
#pragma unroll
    for (int i = 0; i < 4; i++)
#pragma unroll
      for (int j = 0; j < 4; j++){
        int row = m0 + wm * 64 + i * 16 + rj;
        int col = n0 + wn * 64 + j * 16 + lr;
        float bvl = bias[col];
        f16x4 tv;
#pragma unroll
        for (int r = 0; r < 4; r++) tv[r] = (f16)(acc[i][j][r] + bvl);
        *(f16x4*)(ovT + (size_t)col * 8192 + row) = tv;
      }
  }
}

// ---------------- QK^T (per batch, fp32 logits) -- exact R8 ----------------
__global__ __launch_bounds__(512, 2) void qk8p(
    const f16* __restrict__ q, const f16* __restrict__ k, float* __restrict__ Sout)
{
  __shared__ char smem[131072];
  const int s  = swz_lid();               // grid (8, 8, 4)
  const int bx = s & 7, by = (s >> 3) & 7, z = s >> 6;
  const int m0 = by * 256, n0 = bx * 256;
  const f16* A = q + (size_t)z * 2048 * 1024 + (size_t)m0 * 1024;
  const f16* B = k + (size_t)z * 2048 * 1024 + (size_t)n0 * 1024;

  f32x4 acc[8][4];
  gemm_core(A, 1024, B, 1024, 16, smem, acc);

  const int lane = threadIdx.x & 63;
  const int wv_  = threadIdx.x >> 6;
  const int wm = wv_ >> 2, wn = wv_ & 3;
  const int lr = lane & 15, rj = (lane >> 4) * 4;
  float* o = Sout + (size_t)z * 2048 * 2048;
#pragma unroll
  for (int i = 0; i < 8; i++)
#pragma unroll
    for (int j = 0; j < 4; j++){
      int row = m0 + i * 32 + wm * 16 + rj;
      int col = n0 + j * 64 + wn * 16 + lr;
#pragma unroll
      for (int r = 0; r < 4; r++)
        o[(size_t)(row + r) * 2048 + col] = acc[i][j][r];
    }
}

// ---------------- PV (per batch, split-K x2 -> f16 partials) -- exact R8 ----------------
__global__ __launch_bounds__(512, 2) void pv8p(
    const f16* __restrict__ P, const f16* __restrict__ vT, f16* __restrict__ O)
{
  __shared__ char smem[131072];
  const int s  = swz_lid();               // grid (4, 8, 8)
  const int bx = s & 3, by = (s >> 2) & 7, z = s >> 5;
  const int zb = z >> 1, h = z & 1;
  const int m0 = by * 256, n0 = bx * 256;
  const f16* A = P  + (size_t)zb * 2048 * 2048 + (size_t)m0 * 2048 + h * 1024;
  const f16* B = vT + (size_t)n0 * 8192 + (size_t)zb * 2048 + h * 1024;

  f32x4 acc[8][4];
  gemm_core(A, 2048, B, 8192, 16, smem, acc);

  const int lane = threadIdx.x & 63;
  const int wv_  = threadIdx.x >> 6;
  const int wm = wv_ >> 2, wn = wv_ & 3;
  const int lr = lane & 15, rj = (lane >> 4) * 4;
  f16* o = O + (size_t)h * 8388608 + (size_t)zb * 2048 * 1024;
#pragma unroll
  for (int i = 0; i < 8; i++)
#pragma unroll
    for (int j = 0; j < 4; j++){
      int row = m0 + i * 32 + wm * 16 + rj;
      int col = n0 + j * 64 + wn * 16 + lr;
#pragma unroll
      for (int r = 0; r < 4; r++)
        o[(size_t)(row + r) * 1024 + col] = (f16)acc[i][j][r];
    }
}

// ---------------- fp32 -> fp16 convert, 3 tensors in one launch ----------------
__global__ __launch_bounds__(256) void cvt3_f32_f16(
    const float* __restrict__ x0, const float* __restrict__ x1, const float* __restrict__ x2,
    f16* __restrict__ y0, f16* __restrict__ y1, f16* __restrict__ y2){
  const int z = blockIdx.y;
  const float* x = z == 0 ? x0 : z == 1 ? x1 : x2;
  f16* y = z == 0 ? y0 : z == 1 ? y1 : y2;
  int i = (blockIdx.x * 256 + threadIdx.x) * 8;
  float4 a = *(const float4*)(x + i);
  float4 b = *(const float4*)(x + i + 4);
  f16x8 v;
  v[0]=(f16)a.x; v[1]=(f16)a.y; v[2]=(f16)a.z; v[3]=(f16)a.w;
  v[4]=(f16)b.x; v[5]=(f16)b.y; v[6]=(f16)b.z; v[7]=(f16)b.w;
  *(f16x8*)(y + i) = v;
}

// ------------- W [d][f] fp32 -> Wt [f][d] fp16, 3 weights in one launch -------------
__global__ __launch_bounds__(256) void transpose3_cvt_w(
    const float* __restrict__ W0, const float* __restrict__ W1, const float* __restrict__ W2,
    f16* __restrict__ T0, f16* __restrict__ T1, f16* __restrict__ T2, int D){
  const int z = blockIdx.z;
  const float* W = z == 0 ? W0 : z == 1 ? W1 : W2;
  f16* T = z == 0 ? T0 : z == 1 ? T1 : T2;
  __shared__ float t[32][33];
  int tx = threadIdx.x & 31, ty = threadIdx.x >> 5; // 32 x 8
  int bx = blockIdx.x * 32, by = blockIdx.y * 32;
#pragma unroll
  for (int j = 0; j < 4; j++) t[ty + j*8][tx] = W[(size_t)(by + ty + j*8) * D + bx + tx];
  __syncthreads();
#pragma unroll
  for (int j = 0; j < 4; j++){
    float v = t[tx][ty + j*8];
    T[(size_t)(bx + ty + j*8) * D + by + tx] = (f16)v;
  }
}

// ---------------- row softmax, wave-per-row: S fp32 [8192][2048] -> P f16 ----
__global__ __launch_bounds__(256) void softmax_rows(const float* __restrict__ S, f16* __restrict__ P){
  const int row  = blockIdx.x * 4 + (threadIdx.x >> 6);
  const int lane = threadIdx.x & 63;
  const float* x = S + (size_t)row * 2048 + lane * 32;
  float v[32];
  float m = -3.4e38f;
#pragma unroll
  for (int c = 0; c < 8; c++){
    float4 t = *(const float4*)(x + c * 4);
    v[c*4+0] = t.x; v[c*4+1] = t.y; v[c*4+2] = t.z; v[c*4+3] = t.w;
    m = fmaxf(m, fmaxf(fmaxf(t.x, t.y), fmaxf(t.z, t.w)));
  }
#pragma unroll
  for (int o = 32; o; o >>= 1) m = fmaxf(m, __shfl_xor(m, o));
  float ssum = 0.f;
#pragma unroll
  for (int j = 0; j < 32; j++){ v[j] = __expf(v[j] - m); ssum += v[j]; }
#pragma unroll
  for (int o = 32; o; o >>= 1) ssum += __shfl_xor(ssum, o);
  float inv = 1.f / ssum;
  f16* p = P + (size_t)row * 2048 + lane * 32;
#pragma unroll
  for (int c = 0; c < 4; c++){
    f16x8 ov;
#pragma unroll
    for (int j = 0; j < 8; j++) ov[j] = (f16)(v[c*8+j] * inv);
    *(f16x8*)(p + c * 8) = ov;
  }
}

// ---------------- residual + layernorm (sums two f16 partials) ----------------
DEV float wred_sum(float v){
#pragma unroll
  for (int o = 32; o; o >>= 1) v += __shfl_xor(v, o);
  return v;
}

__global__ __launch_bounds__(256) void resid_ln2(const f16* __restrict__ O0,
                                                 const f16* __restrict__ O1,
                                                 const float* __restrict__ query,
                                                 const float* __restrict__ gamma,
                                                 const float* __restrict__ beta,
                                                 float* __restrict__ out){
  const int row = blockIdx.x;
  const int tid = threadIdx.x;
  const size_t base = (size_t)row * 1024 + tid * 4;
  f16x4 o4 = *(const f16x4*)(O0 + base);
  f16x4 p4 = *(const f16x4*)(O1 + base);
  float4 q4 = *(const float4*)(query + base);
  float x[4] = {(float)o4[0] + (float)p4[0] + q4.x,
                (float)o4[1] + (float)p4[1] + q4.y,
                (float)o4[2] + (float)p4[2] + q4.z,
                (float)o4[3] + (float)p4[3] + q4.w};
  float s = 0.f, ss = 0.f;
#pragma unroll
  for (int j = 0; j < 4; j++){ s += x[j]; ss += x[j] * x[j]; }

  __shared__ float red[4];
  s = wred_sum(s);
  if ((tid & 63) == 0) red[tid >> 6] = s;
  __syncthreads();
  s = red[0] + red[1] + red[2] + red[3];
  ss = wred_sum(ss);
  __syncthreads();
  if ((tid & 63) == 0) red[tid >> 6] = ss;
  __syncthreads();
  ss = red[0] + red[1] + red[2] + red[3];

  float mu = s * (1.f / 1024.f);
  float var = ss * (1.f / 1024.f) - mu * mu;
  float rs = rsqrtf(var + 1e-5f);
  float4 g4 = *(const float4*)(gamma + tid * 4);
  float4 b4 = *(const float4*)(beta + tid * 4);
  float4 r;
  r.x = (x[0] - mu) * rs * g4.x + b4.x;
  r.y = (x[1] - mu) * rs * g4.y + b4.y;
  r.z = (x[2] - mu) * rs * g4.z + b4.z;
  r.w = (x[3] - mu) * rs * g4.w + b4.w;
  *(float4*)(out + base) = r;
}

// ---------------- launch ----------------
extern "C" void kernel_launch(void* const* d_in, const int* in_sizes, int n_in,
                              void* d_out, int out_size, void* d_ws, size_t ws_size,
                              hipStream_t stream){
  const float* query  = (const float*)d_in[0];
  const float* key_in = (const float*)d_in[1];
  const float* value  = (const float*)d_in[2];
  const float* Wq = (const float*)d_in[3];
  const float* bq = (const float*)d_in[4];
  const float* Wk = (const float*)d_in[5];
  const float* bk = (const float*)d_in[6];
  const float* Wv = (const float*)d_in[7];
  const float* bv = (const float*)d_in[8];
  const float* gamma = (const float*)d_in[9];
  const float* beta  = (const float*)d_in[10];

  const int B = 4, S = 2048, D = 1024;
  const int M = B * S;                 // 8192 tokens
  const size_t MB = 1ull << 20;
  char* ws = (char*)d_ws;

  f16* qf16 = (f16*)(ws + 0);
  f16* kf16 = (f16*)(ws + 16 * MB);
  f16* vT   = (f16*)(ws + 32 * MB);    // [1024][8192]
  f16* wt_q = (f16*)(ws + 48 * MB);
  f16* wt_k = (f16*)(ws + 50 * MB);
  f16* wt_v = (f16*)(ws + 52 * MB);
  f16* Obuf = (f16*)(ws + 54 * MB);    // O0 @54, O1 @70 (16MB each, f16)
  f16* xq   = (f16*)(ws + 118 * MB);
  f16* xk   = (f16*)(ws + 134 * MB);
  f16* xv   = (f16*)(ws + 150 * MB);
  float* Sbuf = (float*)(ws + 118 * MB);  // 64MB, aliases xq..xv (dead after proj)
  f16*   Pbuf = (f16*)(ws + 182 * MB);    // 32MB

  dim3 blk(256);
  const int nElem = M * D;             // 8388608

  cvt3_f32_f16<<<dim3(nElem / 2048, 3), blk, 0, stream>>>(query, key_in, value, xq, xk, xv);
  transpose3_cvt_w<<<dim3(32, 32, 3), blk, 0, stream>>>(Wq, Wk, Wv, wt_q, wt_k, wt_v, D);

  // fused projections: R10 core, grid (4, 64, 3) = 768 WGs (3 exact rounds)
  proj8p<<<dim3(4, 64, 3), dim3(512), 0, stream>>>(xq, xk, xv, wt_q, wt_k, wt_v,
                                                   bq, bk, bv, qf16, kf16, vT);

  // QK^T per batch: 256 WGs (R8 core)
  qk8p<<<dim3(8, 8, 4), dim3(512), 0, stream>>>(qf16, kf16, Sbuf);

  // wave-per-row softmax: 4 rows/block
  softmax_rows<<<M / 4, blk, 0, stream>>>(Sbuf, Pbuf);

  // PV per batch, split-K x2: 256 WGs, f16 partials (R8 core)
  pv8p<<<dim3(4, 8, 8), dim3(512), 0, stream>>>(Pbuf, vT, Obuf);

  resid_ln2<<<M, blk, 0, stream>>>(Obuf, Obuf + 8388608, query, gamma, beta, (float*)d_out);
}